// Round 7
// baseline (109.597 us; speedup 1.0000x reference)
//
#include <hip/hip_runtime.h>

typedef __attribute__((ext_vector_type(8)))  __bf16 bvec8;
typedef __attribute__((ext_vector_type(4)))  __bf16 bvec4;
typedef __attribute__((ext_vector_type(16))) float  fvec16;
typedef __attribute__((ext_vector_type(8)))  short  svec8;

__device__ __forceinline__ void gload16(const void* g, void* l) {
    __builtin_amdgcn_global_load_lds(
        (const __attribute__((address_space(1))) void*)g,
        (__attribute__((address_space(3))) void*)l,
        16, 0, 0);
}

// ---- pack W[l][j][k][i] fp32 -> Wp bf16, 32x32x16-frag-ready ----
// unit u = (kt16*16 + it2)*64 + lane ; elem e:
//   K = kt16*16 + (lane>>5)*8 + e ; jk = K>>7 ; l = K&127 ; i = it2*32 + (lane&31)
__global__ __launch_bounds__(256) void pack_w(const float* __restrict__ W,
                                              __bf16* __restrict__ Wp) {
    int u = blockIdx.x * 256 + threadIdx.x;
    if (u >= 73728) return;                   // 72 kt16 * 16 it2 * 64
    int lane = u & 63;
    int it2  = (u >> 6) & 15;
    int kt16 = u >> 10;
    int i  = it2 * 32 + (lane & 31);
    int K0 = kt16 * 16 + ((lane >> 5) << 3);
    bvec8 o;
#pragma unroll
    for (int e = 0; e < 8; ++e) {
        int K  = K0 + e;
        int jk = K >> 7;
        int l  = K & 127;
        int j  = (jk * 11) >> 5;              // jk/3 for jk<9
        int k  = jk - 3 * j;
        o[e] = (__bf16)W[((l * 9 + j * 3 + k) << 9) + i];
    }
    *(bvec8*)&Wp[(size_t)u * 8] = o;
}

// ---- main: block = 1 batch x 512 i, 512 thr = 8 waves ----
// wave wv: i-tiles {2wv, 2wv+1} (am=2), both s-tiles (sn=2).
// MFMA: A = W (row=i, from LDS wslot), B = activations (col=s, from ys).
// ys[row=(n*3+j)*7+w][l 0..127], 16B-unit swizzle u^=(row&15); row 147 = zeros.
// K-loop: 72 K16 phases, LDS dbuf W (2x16KB), stage-early / one barrier per phase.
__global__ __launch_bounds__(512, 4) void conv_mfma(
    const float* __restrict__ x, const __bf16* __restrict__ Wp,
    float* __restrict__ out)
{
    extern __shared__ char smem[];
    __bf16* ys = (__bf16*)smem;               // 37888 B (148 rows x 256 B)
    char*  reg2 = smem + 37888;               // 32768 B: xs (build) / wbuf (K-loop)
    __bf16* xs  = (__bf16*)reg2;              // [l 0..255][c=r*7+w], 25088 B used

    const int tid  = threadIdx.x;
    const int lane = tid & 63;
    const int l31  = lane & 31;
    const int ls5  = lane >> 5;
    const int wv   = tid >> 6;                // wave 0..7
    const int b    = blockIdx.x;

    const float* xb = x + (size_t)b * 12544;
    const char*  WpB = (const char*)Wp;

    // ---- pass 1: x (f32) -> xs (bf16), float4-vectorized, coalesced ----
    for (int it = 0; it < 7; ++it) {
        int e4 = it * 512 + tid;
        if (e4 < 3136) {
            const float4 v = ((const float4*)xb)[e4];
            bvec4 pk = { (__bf16)v.x, (__bf16)v.y, (__bf16)v.z, (__bf16)v.w };
            *(bvec4*)&xs[e4 * 4] = pk;
        }
    }
    __syncthreads();

    // ---- pass 2: write-once ys build ----
    // maskA: rA = n+j-1 in [0,7) ; maskB: !(j==0&&n==1) && !(j==2&&n==0), rB=(n+j+5)%7
    for (int it = 0; it < 5; ++it) {
        int up = it * 512 + tid;
        if (up < 2368) {
            int row  = up >> 4;
            int useg = up & 15;
            bvec8 ov;
            if (row >= 147) {
                ov = __builtin_bit_cast(bvec8, (svec8)0);
                row = 147;
            } else {
                int w   = row % 7;
                int njq = row / 7;
                int j   = njq % 3;
                int n   = njq / 3;
                int rA  = n + j - 1;
                bool mA = (unsigned)rA < 7u;
                int rB  = n + j + 5; if (rB >= 7) rB -= 7; if (rB >= 7) rB -= 7;
                bool mB = !((j == 0 && n == 1) || (j == 2 && n == 0));
                int cA  = rA * 7 + w;
                int cB  = rB * 7 + w;
                int l0  = useg * 8;
#pragma unroll
                for (int d = 0; d < 8; ++d) {
                    float fa = mA ? (float)xs[(l0 + d) * 49 + cA] : 0.f;
                    float fb = mB ? (float)xs[(128 + l0 + d) * 49 + cB] : 0.f;
                    ov[d] = (__bf16)(fa + fb);
                }
            }
            *(bvec8*)&ys[(row << 7) + ((useg ^ (row & 15)) << 3)] = ov;
        }
    }

    // ---- per-lane column geometry: s = sn*32 + l31 ----
    int nn21[2], oo[2];
#pragma unroll
    for (int sn = 0; sn < 2; ++sn) {
        int s = sn * 32 + l31;
        int sc = (s < 49) ? s : 48;
        int n = sc / 7;
        nn21[sn] = n * 21;
        oo[sn]   = sc - n * 7;
    }

    fvec16 acc[2][2];
#pragma unroll
    for (int am = 0; am < 2; ++am)
#pragma unroll
        for (int sn = 0; sn < 2; ++sn)
#pragma unroll
            for (int r = 0; r < 16; ++r) acc[am][sn][r] = 0.f;

    __syncthreads();   // ys complete; xs dead -> reg2 becomes wbuf

    // ---- prologue: stage K16 tiles 0,1 into the two 16 KB slots ----
    {
        const char* g0 = WpB + (tid << 4);
        char* d0 = reg2 + (tid << 4);
        gload16(g0, d0);                       // tile 0 lower 8K
        gload16(g0 + 8192, d0 + 8192);         // tile 0 upper 8K
        gload16(g0 + 16384, d0 + 16384);       // tile 1 lower
        gload16(g0 + 24576, d0 + 24576);       // tile 1 upper
    }
    __syncthreads();   // vmcnt(0): tiles 0,1 landed (one-time bubble)

    // ---- K-loop: 72 K16 phases ----
    for (int jk = 0; jk < 9; ++jk) {
        const int j = (jk * 11) >> 5;
        const int k = jk - 3 * j;
        int rowB[2], rx[2];
#pragma unroll
        for (int sn = 0; sn < 2; ++sn) {
            int o  = oo[sn];
            int tw = o + k + 5;
            int w  = tw >= 7 ? tw - 7 : tw;                 // (o+k+5)%7
            int row = nn21[sn] + j * 7 + w;
            if ((k == 0 && o == 0) || (k == 2 && o == 6)) row = 147;  // zero row
            rowB[sn] = row << 7;
            rx[sn]   = row & 15;
        }
#pragma unroll
        for (int q = 0; q < 8; ++q) {
            const int kt = jk * 8 + q;
            if (kt) __syncthreads();           // prev stage landed; prev reads done
            // stage next K16 tile (issue early, waited by next phase's barrier)
            if (kt && kt + 1 < 72) {
                const char* g = WpB + ((size_t)(kt + 1) << 14) + (tid << 4);
                char* d = reg2 + (((kt + 1) & 1) << 14) + (tid << 4);
                gload16(g, d);
                gload16(g + 8192, d + 8192);
            }
            // W fragments (conflict-free stride-1) + activation fragments
            const __bf16* ws = (const __bf16*)(reg2 + ((kt & 1) << 14));
            bvec8 wf[2], bf[2];
#pragma unroll
            for (int am = 0; am < 2; ++am)
                wf[am] = *(const bvec8*)&ws[((wv * 2 + am) << 9) + (lane << 3)];
#pragma unroll
            for (int sn = 0; sn < 2; ++sn) {
                int u = ((q << 1) + ls5) ^ rx[sn];
                bf[sn] = *(const bvec8*)&ys[rowB[sn] + (u << 3)];
            }
            __builtin_amdgcn_s_setprio(1);
            acc[0][0] = __builtin_amdgcn_mfma_f32_32x32x16_bf16(wf[0], bf[0], acc[0][0], 0, 0, 0);
            acc[0][1] = __builtin_amdgcn_mfma_f32_32x32x16_bf16(wf[0], bf[1], acc[0][1], 0, 0, 0);
            acc[1][0] = __builtin_amdgcn_mfma_f32_32x32x16_bf16(wf[1], bf[0], acc[1][0], 0, 0, 0);
            acc[1][1] = __builtin_amdgcn_mfma_f32_32x32x16_bf16(wf[1], bf[1], acc[1][1], 0, 0, 0);
            __builtin_amdgcn_s_setprio(0);
        }
    }

    // ---- epilogue: D row=(r&3)+8*(r>>2)+4*ls5 -> i ; col=l31 -> s ----
    const size_t obase = (size_t)b * 25088;   // 512*49
#pragma unroll
    for (int am = 0; am < 2; ++am) {
        const int i0 = (wv * 2 + am) * 32 + 4 * ls5;
#pragma unroll
        for (int sn = 0; sn < 2; ++sn) {
            const int s = sn * 32 + l31;
            if (sn == 1 && l31 >= 17) continue;   // s >= 49
#pragma unroll
            for (int r = 0; r < 16; ++r) {
                int i = i0 + (r & 3) + 8 * (r >> 2);
                out[obase + (size_t)i * 49 + s] = acc[am][sn][r];
            }
        }
    }
}

extern "C" void kernel_launch(void* const* d_in, const int* in_sizes, int n_in,
                              void* d_out, int out_size, void* d_ws, size_t ws_size,
                              hipStream_t stream) {
    const float* x = (const float*)d_in[0];   // (1024,256,7,7)
    const float* W = (const float*)d_in[1];   // (128,3,3,512)
    float* out = (float*)d_out;               // (1024,512,7,7)
    __bf16* Wp = (__bf16*)d_ws;               // 72*16*64*8 bf16 = 1.18 MB
    (void)in_sizes; (void)n_in; (void)out_size; (void)ws_size;

    hipFuncSetAttribute(reinterpret_cast<const void*>(conv_mfma),
                        hipFuncAttributeMaxDynamicSharedMemorySize, 70656);

    hipLaunchKernelGGL(pack_w, dim3(288), dim3(256), 0, stream, W, Wp);
    hipLaunchKernelGGL(conv_mfma, dim3(1024), dim3(512), 70656, stream, x, Wp, out);
}